// Round 1
// baseline (1103.407 us; speedup 1.0000x reference)
//
#include <hip/hip_runtime.h>

typedef __attribute__((ext_vector_type(8))) short bf16x8;
typedef __attribute__((ext_vector_type(4))) short s16x4;
typedef __attribute__((ext_vector_type(4))) float f32x4;
typedef unsigned short ushort_t;

#define LOG2E 1.44269504088896340736f
#define EXP_BIAS 23.08312066f          /* 16 * LOG2E */
#define Q_SCALE 0.18033688f            /* 0.125 * LOG2E */

// ---------- helpers ----------
__device__ __forceinline__ unsigned short f2bf(float x) {
  unsigned int u = __float_as_uint(x);
  u = (u + 0x7FFFu + ((u >> 16) & 1u)) >> 16;   // RNE
  return (unsigned short)u;
}

__device__ __forceinline__ void async16(void* lds_dst, const void* gsrc) {
  __builtin_amdgcn_global_load_lds(
      (const __attribute__((address_space(1))) void*)gsrc,
      (__attribute__((address_space(3))) void*)lds_dst, 16, 0, 0);
}

// ---------- fp32 -> bf16 row-major (vectorized) ----------
__global__ __launch_bounds__(256) void f32_to_bf16_vec(
    const float* __restrict__ in, ushort_t* __restrict__ out, int n8) {
  int i = blockIdx.x * 256 + threadIdx.x;
  if (i >= n8) return;
  const float4* p = (const float4*)in + (size_t)i * 2;
  float4 a = p[0], b = p[1];
  bf16x8 v;
  v[0] = (short)f2bf(a.x); v[1] = (short)f2bf(a.y);
  v[2] = (short)f2bf(a.z); v[3] = (short)f2bf(a.w);
  v[4] = (short)f2bf(b.x); v[5] = (short)f2bf(b.y);
  v[6] = (short)f2bf(b.z); v[7] = (short)f2bf(b.w);
  *((bf16x8*)out + i) = v;
}

// ---------- transpose fp32 (Kd x N) -> bf16 (Npad x Kd), zero-pad rows >= N ----------
__global__ __launch_bounds__(256) void transpose_w_bf16(
    const float* __restrict__ in, ushort_t* __restrict__ out, int N, int Kd) {
  __shared__ float tile[32][33];
  const int tx = threadIdx.x & 31, ty = threadIdx.x >> 5;
  const int n0 = blockIdx.x * 32, k0 = blockIdx.y * 32;
#pragma unroll
  for (int yy = 0; yy < 32; yy += 8) {
    int k = k0 + ty + yy;
    int n = n0 + tx;
    tile[ty + yy][tx] = (n < N) ? in[(size_t)k * N + n] : 0.f;
  }
  __syncthreads();
#pragma unroll
  for (int yy = 0; yy < 32; yy += 8) {
    int n = n0 + ty + yy;
    int k = k0 + tx;
    out[(size_t)n * Kd + k] = f2bf(tile[tx][ty + yy]);
  }
}

// ---------- 128x128-tile bf16 GEMM, C = A(MxK) @ Bt(NpadxK)^T, fp32 out ----------
__global__ __launch_bounds__(256) void gemm_bt_128(
    const ushort_t* __restrict__ A, const ushort_t* __restrict__ Bt,
    float* __restrict__ C, int N, int K, int ldc) {
  __shared__ __align__(16) char lds[16384];          // A: [0,8K), B: [8K,16K)
  const int tid = threadIdx.x;
  const int lane = tid & 63, wave = tid >> 6;
  const int quad = lane >> 4, col = lane & 15;
  const int bm = blockIdx.x, bn = blockIdx.y;
  const int wr = (wave >> 1) * 64, wc = (wave & 1) * 64;

  const int c0 = tid, c1 = tid + 256;
  const int r0 = c0 >> 2, r1 = c1 >> 2;
  const int l0 = (c0 & 3) ^ ((r0 >> 1) & 3);
  const int l1 = (c1 & 3) ^ ((r1 >> 1) & 3);
  const ushort_t* a0 = A + (size_t)(bm * 128 + r0) * K + l0 * 8;
  const ushort_t* a1 = A + (size_t)(bm * 128 + r1) * K + l1 * 8;
  const ushort_t* b0 = Bt + (size_t)(bn * 128 + r0) * K + l0 * 8;
  const ushort_t* b1 = Bt + (size_t)(bn * 128 + r1) * K + l1 * 8;
  const int wb = wave * 1024;

  f32x4 acc[4][4];
#pragma unroll
  for (int i = 0; i < 4; ++i)
#pragma unroll
    for (int j = 0; j < 4; ++j) acc[i][j] = (f32x4){0.f, 0.f, 0.f, 0.f};

  const int ccsw = (col >> 1) & 3;
  int aoff[4], boff[4];
#pragma unroll
  for (int t = 0; t < 4; ++t) {
    aoff[t] = (wr + t * 16 + col) * 64 + ((quad ^ ccsw) << 4);
    boff[t] = 8192 + (wc + t * 16 + col) * 64 + ((quad ^ ccsw) << 4);
  }

#pragma unroll 1
  for (int k = 0; k < K; k += 32) {
    __syncthreads();
    async16(lds + wb,           a0 + k);
    async16(lds + wb + 4096,    a1 + k);
    async16(lds + 8192 + wb,        b0 + k);
    async16(lds + 8192 + wb + 4096, b1 + k);
    __syncthreads();
    bf16x8 af[4], bfr[4];
#pragma unroll
    for (int t = 0; t < 4; ++t) {
      af[t]  = *(const bf16x8*)(lds + aoff[t]);
      bfr[t] = *(const bf16x8*)(lds + boff[t]);
    }
#pragma unroll
    for (int i = 0; i < 4; ++i)
#pragma unroll
      for (int j = 0; j < 4; ++j)
        acc[i][j] = __builtin_amdgcn_mfma_f32_16x16x32_bf16(af[i], bfr[j], acc[i][j], 0, 0, 0);
  }

#pragma unroll
  for (int i = 0; i < 4; ++i) {
    const int row = bm * 128 + wr + i * 16 + quad * 4;
#pragma unroll
    for (int j = 0; j < 4; ++j) {
      const int cc = bn * 128 + wc + j * 16 + col;
      if (cc < N) {
#pragma unroll
        for (int r = 0; r < 4; ++r)
          C[(size_t)(row + r) * ldc + cc] = acc[i][j][r];
      }
    }
  }
}

// ---------- RoPE + split fused(2048x4672) -> Qr(/8*log2e, bf16), Kr, Vt; zero ssum ----------
__global__ __launch_bounds__(256) void rope_split(
    const float* __restrict__ fused, ushort_t* __restrict__ Qr,
    ushort_t* __restrict__ Kr, ushort_t* __restrict__ Vt, float* __restrict__ ssum) {
  const int spos = blockIdx.x;
  const float* row = fused + (size_t)spos * 4672;
  if (blockIdx.x == 0)
    for (int j = threadIdx.x; j < 2048; j += 256) ssum[j] = 0.f;
  for (int c = threadIdx.x; c < 4672; c += 256) {
    const int hh = c >> 6, d = c & 63, j = d & 31;
    const float x = row[c];
    if (hh == 72) { Vt[(size_t)d * 2048 + spos] = f2bf(x); continue; }
    // 10000^(-j/32) = exp2(-j * log2(10000)/32)
    const float freq = __builtin_amdgcn_exp2f((float)j * -0.41524101186f);
    const float ang = (float)spos * freq;
    float sv, cv;
    __sincosf(ang, &sv, &cv);
    const float partner = (d < 32) ? row[c + 32] : row[c - 32];
    const float val = (d < 32) ? (x * cv - partner * sv) : (x * cv + partner * sv);
    if (hh == 71) Kr[(size_t)spos * 64 + d] = f2bf(val);
    else          Qr[(size_t)spos * 4544 + c] = f2bf(val * Q_SCALE);  // fold 1/sqrt(64)*log2e
  }
}

// ---------- flash MQA attention, fixed-base softmax (C=16), S^T orientation ----------
// block = 128 queries x 1 head; 4 waves x 32 queries, each wave fully independent.
// K (256KB) and V^T (256KB) are L2-resident (MQA, shared by all 71 heads) -> fragments
// are read DIRECTLY from global (no LDS staging, NO barriers in the tile loops).
// Sweep 1: S^T=K·Q^T (keys in regs), p=exp2(sacc-16*log2e) (Q pre-scaled by log2e),
// P^T->pbuf (per-wave LDS, b64 packed), O^T=V^T·P^T.
// Sweep 2: S=Q·K^T recompute, normalized colsums, keys<1920 only (top-k never reads more).
__global__ __launch_bounds__(256, 4) void attn_flash(
    const ushort_t* __restrict__ Qr, const ushort_t* __restrict__ Kr,
    const ushort_t* __restrict__ Vt, ushort_t* __restrict__ merged,
    float* __restrict__ ssum) {
  const int qb = (int)gridDim.x - 1 - (int)blockIdx.x;   // heavy blocks first
  const int h = blockIdx.y;
  const int q0 = qb * 128;
  const int tid = threadIdx.x, wave = tid >> 6, lane = tid & 63;
  const int quad = lane >> 4, col = lane & 15;
  const int qw = q0 + wave * 32;
  const int wtiles = ((qw + 31) >> 6) + 1;               // 64-key tiles this wave needs
  const int ntiles = (qb + 1) * 2;                       // block-level tile count

  __shared__ __align__(16) char pcs[4 * 32 * 72 * 2];    // pbuf (s1) / cs (s2)
  ushort_t* pbuf = (ushort_t*)pcs + wave * (32 * 72);    // P^T: [32 q][64 k] stride 72
  float* cs = (float*)pcs;

  // Q fragments: rows qw+nt*16+col (serve as B in sweep1, A in sweep2)
  bf16x8 qf[2][2];
#pragma unroll
  for (int nt = 0; nt < 2; ++nt)
#pragma unroll
    for (int s = 0; s < 2; ++s)
      qf[nt][s] = *(const bf16x8*)(Qr + (size_t)(qw + nt * 16 + col) * 4544 + h * 64 + s * 32 + quad * 8);

  f32x4 oacc[2][4];                                      // [ntile q][mtile d] of O^T
  float l[2] = {0.f, 0.f};
#pragma unroll
  for (int nt = 0; nt < 2; ++nt)
#pragma unroll
    for (int m = 0; m < 4; ++m) oacc[nt][m] = (f32x4){0.f, 0.f, 0.f, 0.f};

  // ---- sweep 1 (barrier-free) ----
#pragma unroll 1
  for (int t = 0; t < wtiles; ++t) {
    const int kbase = t * 64;

    bf16x8 kf[4][2];                                     // A-frags: rows = keys (direct global)
#pragma unroll
    for (int m = 0; m < 4; ++m) {
      const ushort_t* kr = Kr + (size_t)(kbase + m * 16 + col) * 64 + quad * 8;
      kf[m][0] = *(const bf16x8*)kr;
      kf[m][1] = *(const bf16x8*)(kr + 32);
    }
    // S^T per ntile; pack P^T rows (4 consecutive keys per lane) as b64
#pragma unroll
    for (int nt = 0; nt < 2; ++nt) {
      const int qtop = qw + nt * 16 + 15;
      if (kbase > qtop) continue;
      const int q = qw + nt * 16 + col;
#pragma unroll
      for (int m = 0; m < 4; ++m) {
        const int kb2 = kbase + m * 16;
        f32x4 sacc = (f32x4){0.f, 0.f, 0.f, 0.f};
        if (kb2 <= qtop) {
          __builtin_amdgcn_s_setprio(1);
          sacc = __builtin_amdgcn_mfma_f32_16x16x32_bf16(kf[m][0], qf[nt][0], sacc, 0, 0, 0);
          sacc = __builtin_amdgcn_mfma_f32_16x16x32_bf16(kf[m][1], qf[nt][1], sacc, 0, 0, 0);
          __builtin_amdgcn_s_setprio(0);
        }
        s16x4 pk;
        float ls = 0.f;
#pragma unroll
        for (int r = 0; r < 4; ++r) {
          const int key = kb2 + quad * 4 + r;
          const float px = __builtin_amdgcn_exp2f(sacc[r] - EXP_BIAS);
          const float p = (key <= q) ? px : 0.f;
          ls += p;
          pk[r] = (short)f2bf(p);
        }
        l[nt] += ls;
        *(s16x4*)(pbuf + (nt * 16 + col) * 72 + m * 16 + quad * 4) = pk;
      }
    }
    // PV: O^T += V^T · P^T  (A = V^T d-rows direct from global, B = pbuf q-rows)
#pragma unroll
    for (int ch = 0; ch < 2; ++ch) {
      if (kbase + ch * 32 > qw + 31) continue;
      bf16x8 vf[4];
#pragma unroll
      for (int m = 0; m < 4; ++m)
        vf[m] = *(const bf16x8*)(Vt + (size_t)(m * 16 + col) * 2048 + kbase + ch * 32 + quad * 8);
#pragma unroll
      for (int nt = 0; nt < 2; ++nt) {
        if (kbase + ch * 32 > qw + nt * 16 + 15) continue;
        const bf16x8 pf = *(const bf16x8*)(pbuf + (nt * 16 + col) * 72 + ch * 32 + quad * 8);
        __builtin_amdgcn_s_setprio(1);
#pragma unroll
        for (int m = 0; m < 4; ++m)
          oacc[nt][m] = __builtin_amdgcn_mfma_f32_16x16x32_bf16(vf[m], pf, oacc[nt][m], 0, 0, 0);
        __builtin_amdgcn_s_setprio(0);
      }
    }
  }

  // l: per-lane partials cover keys == quad*4+r (mod 16); reduce across quads
  float invl[2];
#pragma unroll
  for (int nt = 0; nt < 2; ++nt) {
    float v = l[nt];
    v += __shfl_xor(v, 16, 64);
    v += __shfl_xor(v, 32, 64);
    invl[nt] = 1.0f / v;
  }

  // write O^T: lane holds 4 consecutive d for query nt*16+col -> b64 stores
#pragma unroll
  for (int nt = 0; nt < 2; ++nt)
#pragma unroll
    for (int m = 0; m < 4; ++m) {
      s16x4 ok;
#pragma unroll
      for (int r = 0; r < 4; ++r) ok[r] = (short)f2bf(oacc[nt][m][r] * invl[nt]);
      *(s16x4*)(merged + (size_t)(qw + nt * 16 + col) * 4544 + h * 64 + m * 16 + quad * 4) = ok;
    }

  // invl in sweep-2 row layout: query = qw + i*16 + quad*4 + r
  float linv2[2][4];
#pragma unroll
  for (int i = 0; i < 2; ++i)
#pragma unroll
    for (int r = 0; r < 4; ++r) linv2[i][r] = __shfl(invl[i], quad * 4 + r, 16);

  // ---- sweep 2: normalized colsums, keys < 1920 only ----
  __syncthreads();                                   // all pbuf reads done -> reuse as cs
  const int nk2 = min(ntiles * 64, 1920);
  for (int j = tid; j < nk2; j += 256) cs[j] = 0.f;
  __syncthreads();                                   // cs zeroed before atomics

  const int wtiles2 = min(wtiles, 30);
#pragma unroll 1
  for (int t = 0; t < wtiles2; ++t) {
    const int kbase = t * 64;

    bf16x8 kf[4][2];                                 // B-frags now: rows = keys (direct global)
#pragma unroll
    for (int n = 0; n < 4; ++n) {
      const ushort_t* kr = Kr + (size_t)(kbase + n * 16 + col) * 64 + quad * 8;
      kf[n][0] = *(const bf16x8*)kr;
      kf[n][1] = *(const bf16x8*)(kr + 32);
    }
    float accn[4] = {0.f, 0.f, 0.f, 0.f};
#pragma unroll
    for (int i = 0; i < 2; ++i) {
      if (kbase > qw + i * 16 + 15) continue;
      f32x4 sacc[4];
      __builtin_amdgcn_s_setprio(1);
#pragma unroll
      for (int n = 0; n < 4; ++n) {
        sacc[n] = __builtin_amdgcn_mfma_f32_16x16x32_bf16(qf[i][0], kf[n][0],
                    (f32x4){0.f, 0.f, 0.f, 0.f}, 0, 0, 0);
        sacc[n] = __builtin_amdgcn_mfma_f32_16x16x32_bf16(qf[i][1], kf[n][1], sacc[n], 0, 0, 0);
      }
      __builtin_amdgcn_s_setprio(0);
#pragma unroll
      for (int r = 0; r < 4; ++r) {
        const int q = qw + i * 16 + quad * 4 + r;
#pragma unroll
        for (int n = 0; n < 4; ++n) {
          const int key = kbase + n * 16 + col;
          const float px = __builtin_amdgcn_exp2f(sacc[n][r] - EXP_BIAS) * linv2[i][r];
          accn[n] += (key <= q) ? px : 0.f;
        }
      }
    }
#pragma unroll
    for (int n = 0; n < 4; ++n) {
      float v = accn[n];
      v += __shfl_xor(v, 16, 64);
      v += __shfl_xor(v, 32, 64);
      if (quad == 0) atomicAdd(&cs[kbase + n * 16 + col], v);
    }
  }

  __syncthreads();
  for (int j = tid; j < nk2; j += 256) atomicAdd(&ssum[j], cs[j]);
}

// ---------- top-k(128) of ssum[0..1919] -> mask (2049 floats) ----------
__global__ __launch_bounds__(1024) void topk_mask(
    const float* __restrict__ ssum, float* __restrict__ maskout) {
  __shared__ float sv[1920];
  for (int i = threadIdx.x; i < 1920; i += 1024) sv[i] = ssum[i];
  __syncthreads();
  for (int i = threadIdx.x; i < 2049; i += 1024) {
    float o;
    if (i >= 1921) o = 1.f;
    else if (i == 1920) o = 0.f;
    else {
      const float v = sv[i];
      int rank = 0;
      for (int j = 0; j < 1920; ++j) {
        const float w = sv[j];
        rank += (w > v) || (w == v && j < i);
      }
      o = (rank < 128) ? 1.f : 0.f;
    }
    maskout[i] = o;
  }
}

// ---------- launch ----------
extern "C" void kernel_launch(void* const* d_in, const int* in_sizes, int n_in,
                              void* d_out, int out_size, void* d_ws, size_t ws_size,
                              hipStream_t stream) {
  (void)in_sizes; (void)n_in; (void)out_size; (void)ws_size;
  const float* hs      = (const float*)d_in[0];   // 1x2048x4544
  const float* w_qkv   = (const float*)d_in[1];   // 4544x4672
  const float* w_dense = (const float*)d_in[2];   // 4544x4544
  float* out = (float*)d_out;                     // 2048*4544 + 2049

  char* ws = (char*)d_ws;
  constexpr size_t OFF_WT    = 0;                        // 4736x4544 bf16
  constexpr size_t OFF_HSB   = 43040768;                 // 2048x4544 bf16 (reused as merged)
  constexpr size_t OFF_FUSED = OFF_HSB + 18612224;       // 2048x4672 fp32
  constexpr size_t OFF_QR    = OFF_FUSED + 38273024;     // 2048x4544 bf16
  constexpr size_t OFF_KR    = OFF_QR + 18612224;        // 2048x64 bf16
  constexpr size_t OFF_VT    = OFF_KR + 262144;          // 64x2048 bf16
  constexpr size_t OFF_SS    = OFF_VT + 262144;          // 2048 fp32

  ushort_t* wT     = (ushort_t*)(ws + OFF_WT);
  ushort_t* hsb    = (ushort_t*)(ws + OFF_HSB);
  float*    fused  = (float*)(ws + OFF_FUSED);
  ushort_t* qr     = (ushort_t*)(ws + OFF_QR);
  ushort_t* kr     = (ushort_t*)(ws + OFF_KR);
  ushort_t* vt     = (ushort_t*)(ws + OFF_VT);
  float*    ssum   = (float*)(ws + OFF_SS);

  f32_to_bf16_vec<<<4544, 256, 0, stream>>>(hs, hsb, 2048 * 4544 / 8);
  transpose_w_bf16<<<dim3(148, 142), 256, 0, stream>>>(w_qkv, wT, 4672, 4544);
  gemm_bt_128<<<dim3(16, 37), 256, 0, stream>>>(hsb, wT, fused, 4672, 4544, 4672);
  rope_split<<<2048, 256, 0, stream>>>(fused, qr, kr, vt, ssum);
  transpose_w_bf16<<<dim3(144, 142), 256, 0, stream>>>(w_dense, wT, 4544, 4544);
  attn_flash<<<dim3(16, 71), 256, 0, stream>>>(qr, kr, vt, hsb, ssum);
  topk_mask<<<1, 1024, 0, stream>>>(ssum, out + (size_t)2048 * 4544);
  gemm_bt_128<<<dim3(16, 36), 256, 0, stream>>>(hsb, wT, out, 4544, 4544, 4544);
}

// Round 2
// 1026.558 us; speedup vs baseline: 1.0749x; 1.0749x over previous
//
#include <hip/hip_runtime.h>

typedef __attribute__((ext_vector_type(8))) short bf16x8;
typedef __attribute__((ext_vector_type(4))) short s16x4;
typedef __attribute__((ext_vector_type(4))) float f32x4;
typedef unsigned short ushort_t;

#define LOG2E 1.44269504088896340736f
#define EXP_BIAS 23.08312066f          /* 16 * LOG2E */
#define Q_SCALE 0.18033688f            /* 0.125 * LOG2E */

// ---------- helpers ----------
__device__ __forceinline__ unsigned short f2bf(float x) {
  unsigned int u = __float_as_uint(x);
  u = (u + 0x7FFFu + ((u >> 16) & 1u)) >> 16;   // RNE
  return (unsigned short)u;
}

__device__ __forceinline__ void async16(void* lds_dst, const void* gsrc) {
  __builtin_amdgcn_global_load_lds(
      (const __attribute__((address_space(1))) void*)gsrc,
      (__attribute__((address_space(3))) void*)lds_dst, 16, 0, 0);
}

// ---------- fp32 -> bf16 row-major (vectorized) ----------
__global__ __launch_bounds__(256) void f32_to_bf16_vec(
    const float* __restrict__ in, ushort_t* __restrict__ out, int n8) {
  int i = blockIdx.x * 256 + threadIdx.x;
  if (i >= n8) return;
  const float4* p = (const float4*)in + (size_t)i * 2;
  float4 a = p[0], b = p[1];
  bf16x8 v;
  v[0] = (short)f2bf(a.x); v[1] = (short)f2bf(a.y);
  v[2] = (short)f2bf(a.z); v[3] = (short)f2bf(a.w);
  v[4] = (short)f2bf(b.x); v[5] = (short)f2bf(b.y);
  v[6] = (short)f2bf(b.z); v[7] = (short)f2bf(b.w);
  *((bf16x8*)out + i) = v;
}

// ---------- transpose fp32 (Kd x N) -> bf16 (Npad x Kd), zero-pad rows >= N ----------
__global__ __launch_bounds__(256) void transpose_w_bf16(
    const float* __restrict__ in, ushort_t* __restrict__ out, int N, int Kd) {
  __shared__ float tile[32][33];
  const int tx = threadIdx.x & 31, ty = threadIdx.x >> 5;
  const int n0 = blockIdx.x * 32, k0 = blockIdx.y * 32;
#pragma unroll
  for (int yy = 0; yy < 32; yy += 8) {
    int k = k0 + ty + yy;
    int n = n0 + tx;
    tile[ty + yy][tx] = (n < N) ? in[(size_t)k * N + n] : 0.f;
  }
  __syncthreads();
#pragma unroll
  for (int yy = 0; yy < 32; yy += 8) {
    int n = n0 + ty + yy;
    int k = k0 + tx;
    out[(size_t)n * Kd + k] = f2bf(tile[tx][ty + yy]);
  }
}

// ---------- 128x128-tile bf16 GEMM, C = A(MxK) @ Bt(NpadxK)^T, fp32 out ----------
__global__ __launch_bounds__(256) void gemm_bt_128(
    const ushort_t* __restrict__ A, const ushort_t* __restrict__ Bt,
    float* __restrict__ C, int N, int K, int ldc) {
  __shared__ __align__(16) char lds[16384];          // A: [0,8K), B: [8K,16K)
  const int tid = threadIdx.x;
  const int lane = tid & 63, wave = tid >> 6;
  const int quad = lane >> 4, col = lane & 15;
  const int bm = blockIdx.x, bn = blockIdx.y;
  const int wr = (wave >> 1) * 64, wc = (wave & 1) * 64;

  const int c0 = tid, c1 = tid + 256;
  const int r0 = c0 >> 2, r1 = c1 >> 2;
  const int l0 = (c0 & 3) ^ ((r0 >> 1) & 3);
  const int l1 = (c1 & 3) ^ ((r1 >> 1) & 3);
  const ushort_t* a0 = A + (size_t)(bm * 128 + r0) * K + l0 * 8;
  const ushort_t* a1 = A + (size_t)(bm * 128 + r1) * K + l1 * 8;
  const ushort_t* b0 = Bt + (size_t)(bn * 128 + r0) * K + l0 * 8;
  const ushort_t* b1 = Bt + (size_t)(bn * 128 + r1) * K + l1 * 8;
  const int wb = wave * 1024;

  f32x4 acc[4][4];
#pragma unroll
  for (int i = 0; i < 4; ++i)
#pragma unroll
    for (int j = 0; j < 4; ++j) acc[i][j] = (f32x4){0.f, 0.f, 0.f, 0.f};

  const int ccsw = (col >> 1) & 3;
  int aoff[4], boff[4];
#pragma unroll
  for (int t = 0; t < 4; ++t) {
    aoff[t] = (wr + t * 16 + col) * 64 + ((quad ^ ccsw) << 4);
    boff[t] = 8192 + (wc + t * 16 + col) * 64 + ((quad ^ ccsw) << 4);
  }

#pragma unroll 1
  for (int k = 0; k < K; k += 32) {
    __syncthreads();
    async16(lds + wb,           a0 + k);
    async16(lds + wb + 4096,    a1 + k);
    async16(lds + 8192 + wb,        b0 + k);
    async16(lds + 8192 + wb + 4096, b1 + k);
    __syncthreads();
    bf16x8 af[4], bfr[4];
#pragma unroll
    for (int t = 0; t < 4; ++t) {
      af[t]  = *(const bf16x8*)(lds + aoff[t]);
      bfr[t] = *(const bf16x8*)(lds + boff[t]);
    }
#pragma unroll
    for (int i = 0; i < 4; ++i)
#pragma unroll
      for (int j = 0; j < 4; ++j)
        acc[i][j] = __builtin_amdgcn_mfma_f32_16x16x32_bf16(af[i], bfr[j], acc[i][j], 0, 0, 0);
  }

#pragma unroll
  for (int i = 0; i < 4; ++i) {
    const int row = bm * 128 + wr + i * 16 + quad * 4;
#pragma unroll
    for (int j = 0; j < 4; ++j) {
      const int cc = bn * 128 + wc + j * 16 + col;
      if (cc < N) {
#pragma unroll
        for (int r = 0; r < 4; ++r)
          C[(size_t)(row + r) * ldc + cc] = acc[i][j][r];
      }
    }
  }
}

// ---------- RoPE + split fused(2048x4672) -> Qr(/8*log2e, bf16), Kr, Vt; zero ssum ----------
__global__ __launch_bounds__(256) void rope_split(
    const float* __restrict__ fused, ushort_t* __restrict__ Qr,
    ushort_t* __restrict__ Kr, ushort_t* __restrict__ Vt, float* __restrict__ ssum) {
  const int spos = blockIdx.x;
  const float* row = fused + (size_t)spos * 4672;
  if (blockIdx.x == 0)
    for (int j = threadIdx.x; j < 2048; j += 256) ssum[j] = 0.f;
  for (int c = threadIdx.x; c < 4672; c += 256) {
    const int hh = c >> 6, d = c & 63, j = d & 31;
    const float x = row[c];
    if (hh == 72) { Vt[(size_t)d * 2048 + spos] = f2bf(x); continue; }
    // 10000^(-j/32) = exp2(-j * log2(10000)/32)
    const float freq = __builtin_amdgcn_exp2f((float)j * -0.41524101186f);
    const float ang = (float)spos * freq;
    float sv, cv;
    __sincosf(ang, &sv, &cv);
    const float partner = (d < 32) ? row[c + 32] : row[c - 32];
    const float val = (d < 32) ? (x * cv - partner * sv) : (x * cv + partner * sv);
    if (hh == 71) Kr[(size_t)spos * 64 + d] = f2bf(val);
    else          Qr[(size_t)spos * 4544 + c] = f2bf(val * Q_SCALE);  // fold 1/sqrt(64)*log2e
  }
}

// ---------- flash MQA attention, fixed-base softmax (C=16), S^T orientation ----------
// block = 128 queries x 2 heads; 8 waves (waves 0-3: head 2*by, waves 4-7: head 2*by+1),
// each wave owns 32 queries x 1 head. MQA: the staged K/V tile serves BOTH heads ->
// staging bytes + barriers per unit compute are halved vs 1-head blocks.
// Per-tile pipeline (ONE barrier/tile, T14 issue-early/write-late):
//   issue global->reg loads for tile t+1; __syncthreads(); compute tile t from buf[t&1];
//   ds_write regs -> buf[(t+1)&1]   (safe: buf[(t+1)&1] last read before this barrier).
// Sweep 1: S^T=K·Q^T, p=exp2(sacc-16*log2e) (Q pre-scaled by log2e), P^T->pbuf (per-wave),
// O^T=V^T·P^T. Sweep 2: S=Q·K^T recompute, normalized colsums, keys<1920 only.
__global__ __launch_bounds__(512) void attn_flash(
    const ushort_t* __restrict__ Qr, const ushort_t* __restrict__ Kr,
    const ushort_t* __restrict__ Vt, ushort_t* __restrict__ merged,
    float* __restrict__ ssum) {
  const int qb = (int)gridDim.x - 1 - (int)blockIdx.x;   // heavy blocks first
  const int q0 = qb * 128;
  const int tid = threadIdx.x, wave = tid >> 6, lane = tid & 63;
  const int quad = lane >> 4, col = lane & 15;
  const int hw = (int)blockIdx.y * 2 + (wave >> 2);
  const bool hval = (hw < 71);
  const int h = hval ? hw : 0;
  const int qw = q0 + (wave & 3) * 32;
  const int ntiles = (qb + 1) * 2;                       // 64-key tiles

  __shared__ __align__(16) ushort_t kbuf[2][64 * 72];    // K tile: [64 key][64 d] pad 72
  __shared__ __align__(16) ushort_t vbuf[2][64 * 72];    // V^T tile: [64 d][64 key] pad 72
  __shared__ __align__(16) char pcs[8 * 32 * 72 * 2];    // pbuf (s1) / cs (s2)
  ushort_t* pbuf = (ushort_t*)pcs + wave * (32 * 72);    // P^T: [32 q][64 k] stride 72
  float* cs = (float*)pcs;

  // staging: 512 threads x 1 chunk (16B) per matrix per tile; global reads contiguous
  const int srow = tid >> 3, sg = tid & 7;
  const ushort_t* kp = Kr + (size_t)srow * 64 + sg * 8;    // + t*4096
  const ushort_t* vp = Vt + (size_t)srow * 2048 + sg * 8;  // + t*64
  const int sdo = srow * 72 + sg * 8;

  // Q fragments: rows qw+nt*16+col (serve as B in sweep1, A in sweep2)
  bf16x8 qf[2][2];
#pragma unroll
  for (int nt = 0; nt < 2; ++nt)
#pragma unroll
    for (int s = 0; s < 2; ++s)
      qf[nt][s] = *(const bf16x8*)(Qr + (size_t)(qw + nt * 16 + col) * 4544 + h * 64 + s * 32 + quad * 8);

  f32x4 oacc[2][4];                                      // [ntile q][mtile d] of O^T
  float l[2] = {0.f, 0.f};
#pragma unroll
  for (int nt = 0; nt < 2; ++nt)
#pragma unroll
    for (int m = 0; m < 4; ++m) oacc[nt][m] = (f32x4){0.f, 0.f, 0.f, 0.f};

  // ---- sweep 1 ----
  // prologue: stage tile 0
  *(bf16x8*)(kbuf[0] + sdo) = *(const bf16x8*)kp;
  *(bf16x8*)(vbuf[0] + sdo) = *(const bf16x8*)vp;

#pragma unroll 1
  for (int t = 0; t < ntiles; ++t) {
    const int kbase = t * 64;
    const bool more = (t + 1 < ntiles);
    bf16x8 nk, nv;
    if (more) {                                          // issue next-tile loads early
      nk = *(const bf16x8*)(kp + (size_t)(t + 1) * 4096);
      nv = *(const bf16x8*)(vp + (t + 1) * 64);
    }
    __syncthreads();                                     // buf[t&1] ready
    if (hval && kbase <= qw + 31) {
      const ushort_t* kb = kbuf[t & 1];
      const ushort_t* vb = vbuf[t & 1];
      bf16x8 kf[4][2];                                   // A-frags: rows = keys
#pragma unroll
      for (int m = 0; m < 4; ++m) {
        kf[m][0] = *(const bf16x8*)(kb + (m * 16 + col) * 72 + quad * 8);
        kf[m][1] = *(const bf16x8*)(kb + (m * 16 + col) * 72 + 32 + quad * 8);
      }
      // S^T per ntile; pack P^T rows (4 consecutive keys per lane) as b64
#pragma unroll
      for (int nt = 0; nt < 2; ++nt) {
        const int qtop = qw + nt * 16 + 15;
        if (kbase > qtop) continue;
        const int q = qw + nt * 16 + col;
#pragma unroll
        for (int m = 0; m < 4; ++m) {
          const int kb2 = kbase + m * 16;
          f32x4 sacc = (f32x4){0.f, 0.f, 0.f, 0.f};
          if (kb2 <= qtop) {
            sacc = __builtin_amdgcn_mfma_f32_16x16x32_bf16(kf[m][0], qf[nt][0], sacc, 0, 0, 0);
            sacc = __builtin_amdgcn_mfma_f32_16x16x32_bf16(kf[m][1], qf[nt][1], sacc, 0, 0, 0);
          }
          s16x4 pk;
          float ls = 0.f;
#pragma unroll
          for (int r = 0; r < 4; ++r) {
            const int key = kb2 + quad * 4 + r;
            const float px = __builtin_amdgcn_exp2f(sacc[r] - EXP_BIAS);
            const float p = (key <= q) ? px : 0.f;
            ls += p;
            pk[r] = (short)f2bf(p);
          }
          l[nt] += ls;
          *(s16x4*)(pbuf + (nt * 16 + col) * 72 + m * 16 + quad * 4) = pk;
        }
      }
      // PV: O^T += V^T · P^T  (A = vbuf d-rows, B = pbuf q-rows)
#pragma unroll
      for (int ch = 0; ch < 2; ++ch) {
        if (kbase + ch * 32 > qw + 31) continue;
        bf16x8 vf[4];
#pragma unroll
        for (int m = 0; m < 4; ++m)
          vf[m] = *(const bf16x8*)(vb + (m * 16 + col) * 72 + ch * 32 + quad * 8);
#pragma unroll
        for (int nt = 0; nt < 2; ++nt) {
          if (kbase + ch * 32 > qw + nt * 16 + 15) continue;
          const bf16x8 pf = *(const bf16x8*)(pbuf + (nt * 16 + col) * 72 + ch * 32 + quad * 8);
#pragma unroll
          for (int m = 0; m < 4; ++m)
            oacc[nt][m] = __builtin_amdgcn_mfma_f32_16x16x32_bf16(vf[m], pf, oacc[nt][m], 0, 0, 0);
        }
      }
    }
    if (more) {                                          // write-late into other buffer
      *(bf16x8*)(kbuf[(t + 1) & 1] + sdo) = nk;
      *(bf16x8*)(vbuf[(t + 1) & 1] + sdo) = nv;
    }
  }

  // l: per-lane partials cover keys == quad*4+r (mod 16); reduce across quads
  float invl[2];
#pragma unroll
  for (int nt = 0; nt < 2; ++nt) {
    float v = l[nt];
    v += __shfl_xor(v, 16, 64);
    v += __shfl_xor(v, 32, 64);
    invl[nt] = 1.0f / v;
  }

  // write O^T: lane holds 4 consecutive d for query nt*16+col -> b64 stores
  if (hval) {
#pragma unroll
    for (int nt = 0; nt < 2; ++nt)
#pragma unroll
      for (int m = 0; m < 4; ++m) {
        s16x4 ok;
#pragma unroll
        for (int r = 0; r < 4; ++r) ok[r] = (short)f2bf(oacc[nt][m][r] * invl[nt]);
        *(s16x4*)(merged + (size_t)(qw + nt * 16 + col) * 4544 + h * 64 + m * 16 + quad * 4) = ok;
      }
  }

  // invl in sweep-2 row layout: query = qw + i*16 + quad*4 + r
  float linv2[2][4];
#pragma unroll
  for (int i = 0; i < 2; ++i)
#pragma unroll
    for (int r = 0; r < 4; ++r) linv2[i][r] = __shfl(invl[i], quad * 4 + r, 16);

  // ---- sweep 2: normalized colsums, keys < 1920 only ----
  __syncthreads();                                   // all sweep-1 LDS reads done
  const int nk2 = min(ntiles * 64, 1920);
  const int nt2 = min(ntiles, 30);
  for (int j = tid; j < nk2; j += 512) cs[j] = 0.f;
  // prologue: stage K tile 0
  *(bf16x8*)(kbuf[0] + sdo) = *(const bf16x8*)kp;

#pragma unroll 1
  for (int t = 0; t < nt2; ++t) {
    const int kbase = t * 64;
    const bool more = (t + 1 < nt2);
    bf16x8 nk;
    if (more) nk = *(const bf16x8*)(kp + (size_t)(t + 1) * 4096);
    __syncthreads();                                 // kbuf[t&1] ready, cs zeroed (t==0)
    if (hval && kbase <= qw + 31) {
      const ushort_t* kb = kbuf[t & 1];
      bf16x8 kf[4][2];                               // B-frags now: rows = keys
#pragma unroll
      for (int n = 0; n < 4; ++n) {
        kf[n][0] = *(const bf16x8*)(kb + (n * 16 + col) * 72 + quad * 8);
        kf[n][1] = *(const bf16x8*)(kb + (n * 16 + col) * 72 + 32 + quad * 8);
      }
      float accn[4] = {0.f, 0.f, 0.f, 0.f};
#pragma unroll
      for (int i = 0; i < 2; ++i) {
        if (kbase > qw + i * 16 + 15) continue;
        f32x4 sacc[4];
#pragma unroll
        for (int n = 0; n < 4; ++n) {
          sacc[n] = __builtin_amdgcn_mfma_f32_16x16x32_bf16(qf[i][0], kf[n][0],
                      (f32x4){0.f, 0.f, 0.f, 0.f}, 0, 0, 0);
          sacc[n] = __builtin_amdgcn_mfma_f32_16x16x32_bf16(qf[i][1], kf[n][1], sacc[n], 0, 0, 0);
        }
#pragma unroll
        for (int r = 0; r < 4; ++r) {
          const int q = qw + i * 16 + quad * 4 + r;
#pragma unroll
          for (int n = 0; n < 4; ++n) {
            const int key = kbase + n * 16 + col;
            const float px = __builtin_amdgcn_exp2f(sacc[n][r] - EXP_BIAS) * linv2[i][r];
            accn[n] += (key <= q) ? px : 0.f;
          }
        }
      }
#pragma unroll
      for (int n = 0; n < 4; ++n) {
        float v = accn[n];
        v += __shfl_xor(v, 16, 64);
        v += __shfl_xor(v, 32, 64);
        if (quad == 0) atomicAdd(&cs[kbase + n * 16 + col], v);
      }
    }
    if (more) *(bf16x8*)(kbuf[(t + 1) & 1] + sdo) = nk;
  }

  __syncthreads();
  for (int j = tid; j < nk2; j += 512) atomicAdd(&ssum[j], cs[j]);
}

// ---------- top-k(128) of ssum[0..1919] -> mask (2049 floats) ----------
__global__ __launch_bounds__(1024) void topk_mask(
    const float* __restrict__ ssum, float* __restrict__ maskout) {
  __shared__ float sv[1920];
  for (int i = threadIdx.x; i < 1920; i += 1024) sv[i] = ssum[i];
  __syncthreads();
  for (int i = threadIdx.x; i < 2049; i += 1024) {
    float o;
    if (i >= 1921) o = 1.f;
    else if (i == 1920) o = 0.f;
    else {
      const float v = sv[i];
      int rank = 0;
      for (int j = 0; j < 1920; ++j) {
        const float w = sv[j];
        rank += (w > v) || (w == v && j < i);
      }
      o = (rank < 128) ? 1.f : 0.f;
    }
    maskout[i] = o;
  }
}

// ---------- launch ----------
extern "C" void kernel_launch(void* const* d_in, const int* in_sizes, int n_in,
                              void* d_out, int out_size, void* d_ws, size_t ws_size,
                              hipStream_t stream) {
  (void)in_sizes; (void)n_in; (void)out_size; (void)ws_size;
  const float* hs      = (const float*)d_in[0];   // 1x2048x4544
  const float* w_qkv   = (const float*)d_in[1];   // 4544x4672
  const float* w_dense = (const float*)d_in[2];   // 4544x4544
  float* out = (float*)d_out;                     // 2048*4544 + 2049

  char* ws = (char*)d_ws;
  constexpr size_t OFF_WT    = 0;                        // 4736x4544 bf16
  constexpr size_t OFF_HSB   = 43040768;                 // 2048x4544 bf16 (reused as merged)
  constexpr size_t OFF_FUSED = OFF_HSB + 18612224;       // 2048x4672 fp32
  constexpr size_t OFF_QR    = OFF_FUSED + 38273024;     // 2048x4544 bf16
  constexpr size_t OFF_KR    = OFF_QR + 18612224;        // 2048x64 bf16
  constexpr size_t OFF_VT    = OFF_KR + 262144;          // 64x2048 bf16
  constexpr size_t OFF_SS    = OFF_VT + 262144;          // 2048 fp32

  ushort_t* wT     = (ushort_t*)(ws + OFF_WT);
  ushort_t* hsb    = (ushort_t*)(ws + OFF_HSB);
  float*    fused  = (float*)(ws + OFF_FUSED);
  ushort_t* qr     = (ushort_t*)(ws + OFF_QR);
  ushort_t* kr     = (ushort_t*)(ws + OFF_KR);
  ushort_t* vt     = (ushort_t*)(ws + OFF_VT);
  float*    ssum   = (float*)(ws + OFF_SS);

  f32_to_bf16_vec<<<4544, 256, 0, stream>>>(hs, hsb, 2048 * 4544 / 8);
  transpose_w_bf16<<<dim3(148, 142), 256, 0, stream>>>(w_qkv, wT, 4672, 4544);
  gemm_bt_128<<<dim3(16, 37), 256, 0, stream>>>(hsb, wT, fused, 4672, 4544, 4672);
  rope_split<<<2048, 256, 0, stream>>>(fused, qr, kr, vt, ssum);
  transpose_w_bf16<<<dim3(144, 142), 256, 0, stream>>>(w_dense, wT, 4544, 4544);
  attn_flash<<<dim3(16, 36), 512, 0, stream>>>(qr, kr, vt, hsb, ssum);
  topk_mask<<<1, 1024, 0, stream>>>(ssum, out + (size_t)2048 * 4544);
  gemm_bt_128<<<dim3(16, 36), 256, 0, stream>>>(hsb, wT, out, 4544, 4544, 4544);
}

// Round 3
// 930.658 us; speedup vs baseline: 1.1856x; 1.1030x over previous
//
#include <hip/hip_runtime.h>

typedef __attribute__((ext_vector_type(8))) short bf16x8;
typedef __attribute__((ext_vector_type(4))) short s16x4;
typedef __attribute__((ext_vector_type(4))) float f32x4;
typedef unsigned short ushort_t;

#define LOG2E 1.44269504088896340736f
#define EXP_BIAS 23.08312066f          /* 16 * LOG2E */
#define Q_SCALE 0.18033688f            /* 0.125 * LOG2E */

// ---------- helpers ----------
__device__ __forceinline__ unsigned short f2bf(float x) {
  unsigned int u = __float_as_uint(x);
  u = (u + 0x7FFFu + ((u >> 16) & 1u)) >> 16;   // RNE
  return (unsigned short)u;
}

__device__ __forceinline__ void async16(void* lds_dst, const void* gsrc) {
  __builtin_amdgcn_global_load_lds(
      (const __attribute__((address_space(1))) void*)gsrc,
      (__attribute__((address_space(3))) void*)lds_dst, 16, 0, 0);
}

// ---------- fp32 -> bf16 row-major (vectorized) ----------
__global__ __launch_bounds__(256) void f32_to_bf16_vec(
    const float* __restrict__ in, ushort_t* __restrict__ out, int n8) {
  int i = blockIdx.x * 256 + threadIdx.x;
  if (i >= n8) return;
  const float4* p = (const float4*)in + (size_t)i * 2;
  float4 a = p[0], b = p[1];
  bf16x8 v;
  v[0] = (short)f2bf(a.x); v[1] = (short)f2bf(a.y);
  v[2] = (short)f2bf(a.z); v[3] = (short)f2bf(a.w);
  v[4] = (short)f2bf(b.x); v[5] = (short)f2bf(b.y);
  v[6] = (short)f2bf(b.z); v[7] = (short)f2bf(b.w);
  *((bf16x8*)out + i) = v;
}

// ---------- transpose fp32 (Kd x N) -> bf16 (Npad x Kd), zero-pad rows >= N ----------
__global__ __launch_bounds__(256) void transpose_w_bf16(
    const float* __restrict__ in, ushort_t* __restrict__ out, int N, int Kd) {
  __shared__ float tile[32][33];
  const int tx = threadIdx.x & 31, ty = threadIdx.x >> 5;
  const int n0 = blockIdx.x * 32, k0 = blockIdx.y * 32;
#pragma unroll
  for (int yy = 0; yy < 32; yy += 8) {
    int k = k0 + ty + yy;
    int n = n0 + tx;
    tile[ty + yy][tx] = (n < N) ? in[(size_t)k * N + n] : 0.f;
  }
  __syncthreads();
#pragma unroll
  for (int yy = 0; yy < 32; yy += 8) {
    int n = n0 + ty + yy;
    int k = k0 + tx;
    out[(size_t)n * Kd + k] = f2bf(tile[tx][ty + yy]);
  }
}

// ---------- 128x128-tile bf16 GEMM, C = A(MxK) @ Bt(NpadxK)^T, fp32 out ----------
// split==1: gridDim.x = 2*Mtiles; blockIdx.x&1 selects K-half and output buffer
// (C0 or C1). Halves are summed by the CONSUMER (no atomics, no zeroing).
// Rationale: at M=2048 a 16xN grid is only 2.3 blocks/CU (the m102 "320 TF"
// regime); split-K=2 doubles blocks/CU to 4.6 (the ~833 TF regime).
__global__ __launch_bounds__(256) void gemm_bt_128(
    const ushort_t* __restrict__ A, const ushort_t* __restrict__ Bt,
    float* __restrict__ C0, float* __restrict__ C1,
    int N, int K, int ldc, int split) {
  __shared__ __align__(16) char lds[16384];          // A: [0,8K), B: [8K,16K)
  const int tid = threadIdx.x;
  const int lane = tid & 63, wave = tid >> 6;
  const int quad = lane >> 4, col = lane & 15;
  const int bm = split ? ((int)blockIdx.x >> 1) : (int)blockIdx.x;
  const int half = split ? ((int)blockIdx.x & 1) : 0;
  const int bn = blockIdx.y;
  float* __restrict__ C = half ? C1 : C0;
  const int kh = K >> 1;                             // 2272 = 71*32 exact
  const int ks = half * kh;
  const int ke = split ? (ks + kh) : K;
  const int wr = (wave >> 1) * 64, wc = (wave & 1) * 64;

  const int c0 = tid, c1 = tid + 256;
  const int r0 = c0 >> 2, r1 = c1 >> 2;
  const int l0 = (c0 & 3) ^ ((r0 >> 1) & 3);
  const int l1 = (c1 & 3) ^ ((r1 >> 1) & 3);
  const ushort_t* a0 = A + (size_t)(bm * 128 + r0) * K + l0 * 8;
  const ushort_t* a1 = A + (size_t)(bm * 128 + r1) * K + l1 * 8;
  const ushort_t* b0 = Bt + (size_t)(bn * 128 + r0) * K + l0 * 8;
  const ushort_t* b1 = Bt + (size_t)(bn * 128 + r1) * K + l1 * 8;
  const int wb = wave * 1024;

  f32x4 acc[4][4];
#pragma unroll
  for (int i = 0; i < 4; ++i)
#pragma unroll
    for (int j = 0; j < 4; ++j) acc[i][j] = (f32x4){0.f, 0.f, 0.f, 0.f};

  const int ccsw = (col >> 1) & 3;
  int aoff[4], boff[4];
#pragma unroll
  for (int t = 0; t < 4; ++t) {
    aoff[t] = (wr + t * 16 + col) * 64 + ((quad ^ ccsw) << 4);
    boff[t] = 8192 + (wc + t * 16 + col) * 64 + ((quad ^ ccsw) << 4);
  }

#pragma unroll 1
  for (int k = ks; k < ke; k += 32) {
    __syncthreads();
    async16(lds + wb,           a0 + k);
    async16(lds + wb + 4096,    a1 + k);
    async16(lds + 8192 + wb,        b0 + k);
    async16(lds + 8192 + wb + 4096, b1 + k);
    __syncthreads();
    bf16x8 af[4], bfr[4];
#pragma unroll
    for (int t = 0; t < 4; ++t) {
      af[t]  = *(const bf16x8*)(lds + aoff[t]);
      bfr[t] = *(const bf16x8*)(lds + boff[t]);
    }
#pragma unroll
    for (int i = 0; i < 4; ++i)
#pragma unroll
      for (int j = 0; j < 4; ++j)
        acc[i][j] = __builtin_amdgcn_mfma_f32_16x16x32_bf16(af[i], bfr[j], acc[i][j], 0, 0, 0);
  }

#pragma unroll
  for (int i = 0; i < 4; ++i) {
    const int row = bm * 128 + wr + i * 16 + quad * 4;
#pragma unroll
    for (int j = 0; j < 4; ++j) {
      const int cc = bn * 128 + wc + j * 16 + col;
      if (cc < N) {
#pragma unroll
        for (int r = 0; r < 4; ++r)
          C[(size_t)(row + r) * ldc + cc] = acc[i][j][r];
      }
    }
  }
}

// ---------- out[i] += src[i], float4 ----------
__global__ __launch_bounds__(256) void add_inplace_f4(
    float* __restrict__ dst, const float* __restrict__ src, int n4) {
  int i = blockIdx.x * 256 + threadIdx.x;
  if (i >= n4) return;
  float4 a = ((const float4*)dst)[i];
  float4 b = ((const float4*)src)[i];
  a.x += b.x; a.y += b.y; a.z += b.z; a.w += b.w;
  ((float4*)dst)[i] = a;
}

// ---------- RoPE + split fused(2048x4672) -> Qr(/8*log2e, bf16), Kr, Vt; zero ssum ----------
// two==1: fused = f0 + f1 (split-K GEMM halves summed here, fused into the pass)
__global__ __launch_bounds__(256) void rope_split(
    const float* __restrict__ f0, const float* __restrict__ f1, int two,
    ushort_t* __restrict__ Qr, ushort_t* __restrict__ Kr,
    ushort_t* __restrict__ Vt, float* __restrict__ ssum) {
  const int spos = blockIdx.x;
  const float* row0 = f0 + (size_t)spos * 4672;
  const float* row1 = f1 + (size_t)spos * 4672;
  if (blockIdx.x == 0)
    for (int j = threadIdx.x; j < 2048; j += 256) ssum[j] = 0.f;
  for (int c = threadIdx.x; c < 4672; c += 256) {
    const int hh = c >> 6, d = c & 63, j = d & 31;
    const float x = two ? (row0[c] + row1[c]) : row0[c];
    if (hh == 72) { Vt[(size_t)d * 2048 + spos] = f2bf(x); continue; }
    // 10000^(-j/32) = exp2(-j * log2(10000)/32)
    const float freq = __builtin_amdgcn_exp2f((float)j * -0.41524101186f);
    const float ang = (float)spos * freq;
    float sv, cv;
    __sincosf(ang, &sv, &cv);
    const int cp = (d < 32) ? c + 32 : c - 32;
    const float partner = two ? (row0[cp] + row1[cp]) : row0[cp];
    const float val = (d < 32) ? (x * cv - partner * sv) : (x * cv + partner * sv);
    if (hh == 71) Kr[(size_t)spos * 64 + d] = f2bf(val);
    else          Qr[(size_t)spos * 4544 + c] = f2bf(val * Q_SCALE);  // fold 1/sqrt(64)*log2e
  }
}

// ---------- flash MQA attention, fixed-base softmax (C=16), S^T orientation ----------
// Round-0 structure (best measured: 256 thr, 1 head/block, 2 barriers/tile, 36.9KB LDS
// = 4 blocks/CU) + local deltas: exp bias fold (Q pre-scaled by log2e), zero-store for
// fully-above-diagonal 16-key blocks (skip exp), cmp-free path for fully-below-diagonal
// blocks, sweep-2 capped at keys<1920 with per-block skip.
__global__ __launch_bounds__(256) void attn_flash(
    const ushort_t* __restrict__ Qr, const ushort_t* __restrict__ Kr,
    const ushort_t* __restrict__ Vt, ushort_t* __restrict__ merged,
    float* __restrict__ ssum) {
  const int qb = (int)gridDim.x - 1 - (int)blockIdx.x;   // heavy blocks first
  const int h = blockIdx.y;
  const int q0 = qb * 128;
  const int tid = threadIdx.x, wave = tid >> 6, lane = tid & 63;
  const int quad = lane >> 4, col = lane & 15;
  const int qw = q0 + wave * 32;
  const int ntiles = (qb + 1) * 2;                       // 64-key tiles

  __shared__ __align__(16) ushort_t kbuf[64 * 72];
  __shared__ __align__(16) ushort_t vbuf[64 * 72];
  __shared__ __align__(16) char pcs[4 * 32 * 72 * 2];    // pbuf (s1) / cs (s2)
  ushort_t* pbuf = (ushort_t*)pcs + wave * (32 * 72);    // P^T: [32 q][64 k] stride 72
  float* cs = (float*)pcs;

  const int c0 = tid * 2;
  const int srow = c0 >> 3, sg = c0 & 7;

  // Q fragments: rows qw+nt*16+col (serve as B in sweep1, A in sweep2)
  bf16x8 qf[2][2];
#pragma unroll
  for (int nt = 0; nt < 2; ++nt)
#pragma unroll
    for (int s = 0; s < 2; ++s)
      qf[nt][s] = *(const bf16x8*)(Qr + (size_t)(qw + nt * 16 + col) * 4544 + h * 64 + s * 32 + quad * 8);

  f32x4 oacc[2][4];                                      // [ntile q][mtile d] of O^T
  float l[2] = {0.f, 0.f};
#pragma unroll
  for (int nt = 0; nt < 2; ++nt)
#pragma unroll
    for (int m = 0; m < 4; ++m) oacc[nt][m] = (f32x4){0.f, 0.f, 0.f, 0.f};

  // ---- sweep 1 ----
  for (int t = 0; t < ntiles; ++t) {
    const int kbase = t * 64;
    __syncthreads();
    {
      const ushort_t* ks = Kr + (size_t)(kbase + srow) * 64 + sg * 8;
      ushort_t* kd = kbuf + srow * 72 + sg * 8;
      *(bf16x8*)kd = *(const bf16x8*)ks;
      *(bf16x8*)(kd + 8) = *(const bf16x8*)(ks + 8);
      const ushort_t* vs = Vt + (size_t)srow * 2048 + kbase + sg * 8;
      ushort_t* vd = vbuf + srow * 72 + sg * 8;
      *(bf16x8*)vd = *(const bf16x8*)vs;
      *(bf16x8*)(vd + 8) = *(const bf16x8*)(vs + 8);
    }
    __syncthreads();
    if (kbase > qw + 31) continue;                       // wave fully masked

    bf16x8 kf[4][2];                                     // A-frags: rows = keys
#pragma unroll
    for (int m = 0; m < 4; ++m) {
      kf[m][0] = *(const bf16x8*)(kbuf + (m * 16 + col) * 72 + quad * 8);
      kf[m][1] = *(const bf16x8*)(kbuf + (m * 16 + col) * 72 + 32 + quad * 8);
    }
    // S^T per ntile; pack P^T rows (4 consecutive keys per lane) as b64
#pragma unroll
    for (int nt = 0; nt < 2; ++nt) {
      const int qmin = qw + nt * 16;
      const int qtop = qmin + 15;
      if (kbase > qtop) continue;
      const int q = qmin + col;
#pragma unroll
      for (int m = 0; m < 4; ++m) {
        const int kb2 = kbase + m * 16;
        s16x4 pk;
        if (kb2 > qtop) {                                // fully above diagonal: p == 0
          pk[0] = 0; pk[1] = 0; pk[2] = 0; pk[3] = 0;
          *(s16x4*)(pbuf + (nt * 16 + col) * 72 + m * 16 + quad * 4) = pk;
          continue;
        }
        f32x4 sacc = (f32x4){0.f, 0.f, 0.f, 0.f};
        sacc = __builtin_amdgcn_mfma_f32_16x16x32_bf16(kf[m][0], qf[nt][0], sacc, 0, 0, 0);
        sacc = __builtin_amdgcn_mfma_f32_16x16x32_bf16(kf[m][1], qf[nt][1], sacc, 0, 0, 0);
        float ls = 0.f;
        if (kb2 + 15 <= qmin) {                          // fully below diagonal: no mask
#pragma unroll
          for (int r = 0; r < 4; ++r) {
            const float px = __builtin_amdgcn_exp2f(sacc[r] - EXP_BIAS);
            ls += px;
            pk[r] = (short)f2bf(px);
          }
        } else {                                         // diagonal block: per-element mask
#pragma unroll
          for (int r = 0; r < 4; ++r) {
            const int key = kb2 + quad * 4 + r;
            const float px = __builtin_amdgcn_exp2f(sacc[r] - EXP_BIAS);
            const float p = (key <= q) ? px : 0.f;
            ls += p;
            pk[r] = (short)f2bf(p);
          }
        }
        l[nt] += ls;
        *(s16x4*)(pbuf + (nt * 16 + col) * 72 + m * 16 + quad * 4) = pk;
      }
    }
    // PV: O^T += V^T · P^T  (A = vbuf d-rows, B = pbuf q-rows)
#pragma unroll
    for (int ch = 0; ch < 2; ++ch) {
      if (kbase + ch * 32 > qw + 31) continue;
      bf16x8 vf[4];
#pragma unroll
      for (int m = 0; m < 4; ++m)
        vf[m] = *(const bf16x8*)(vbuf + (m * 16 + col) * 72 + ch * 32 + quad * 8);
#pragma unroll
      for (int nt = 0; nt < 2; ++nt) {
        if (kbase + ch * 32 > qw + nt * 16 + 15) continue;
        const bf16x8 pf = *(const bf16x8*)(pbuf + (nt * 16 + col) * 72 + ch * 32 + quad * 8);
#pragma unroll
        for (int m = 0; m < 4; ++m)
          oacc[nt][m] = __builtin_amdgcn_mfma_f32_16x16x32_bf16(vf[m], pf, oacc[nt][m], 0, 0, 0);
      }
    }
  }

  // l: per-lane partials cover keys == quad*4+r (mod 16); reduce across quads
  float invl[2];
#pragma unroll
  for (int nt = 0; nt < 2; ++nt) {
    float v = l[nt];
    v += __shfl_xor(v, 16, 64);
    v += __shfl_xor(v, 32, 64);
    invl[nt] = 1.0f / v;
  }

  // write O^T: lane holds 4 consecutive d for query nt*16+col -> b64 stores
#pragma unroll
  for (int nt = 0; nt < 2; ++nt)
#pragma unroll
    for (int m = 0; m < 4; ++m) {
      s16x4 ok;
#pragma unroll
      for (int r = 0; r < 4; ++r) ok[r] = (short)f2bf(oacc[nt][m][r] * invl[nt]);
      *(s16x4*)(merged + (size_t)(qw + nt * 16 + col) * 4544 + h * 64 + m * 16 + quad * 4) = ok;
    }

  // invl in sweep-2 row layout: query = qw + i*16 + quad*4 + r
  float linv2[2][4];
#pragma unroll
  for (int i = 0; i < 2; ++i)
#pragma unroll
    for (int r = 0; r < 4; ++r) linv2[i][r] = __shfl(invl[i], quad * 4 + r, 16);

  // ---- sweep 2: normalized colsums, keys < 1920 only ----
  __syncthreads();                                   // pbuf reads done -> reuse as cs
  const int nk2 = min(ntiles * 64, 1920);
  const int nt2 = min(ntiles, 30);
  for (int j = tid; j < nk2; j += 256) cs[j] = 0.f;

  for (int t = 0; t < nt2; ++t) {
    const int kbase = t * 64;
    __syncthreads();
    {
      const ushort_t* ks = Kr + (size_t)(kbase + srow) * 64 + sg * 8;
      ushort_t* kd = kbuf + srow * 72 + sg * 8;
      *(bf16x8*)kd = *(const bf16x8*)ks;
      *(bf16x8*)(kd + 8) = *(const bf16x8*)(ks + 8);
    }
    __syncthreads();
    if (kbase > qw + 31) continue;

    bf16x8 kf[4][2];                                 // B-frags now: rows = keys
#pragma unroll
    for (int n = 0; n < 4; ++n) {
      kf[n][0] = *(const bf16x8*)(kbuf + (n * 16 + col) * 72 + quad * 8);
      kf[n][1] = *(const bf16x8*)(kbuf + (n * 16 + col) * 72 + 32 + quad * 8);
    }
    float accn[4] = {0.f, 0.f, 0.f, 0.f};
#pragma unroll
    for (int i = 0; i < 2; ++i) {
      const int qmin = qw + i * 16;
      const int qmax = qmin + 15;
      if (kbase > qmax) continue;
#pragma unroll
      for (int n = 0; n < 4; ++n) {
        const int kb2 = kbase + n * 16;
        if (kb2 > qmax) continue;                    // block fully masked: contributes 0
        f32x4 sacc = __builtin_amdgcn_mfma_f32_16x16x32_bf16(qf[i][0], kf[n][0],
                       (f32x4){0.f, 0.f, 0.f, 0.f}, 0, 0, 0);
        sacc = __builtin_amdgcn_mfma_f32_16x16x32_bf16(qf[i][1], kf[n][1], sacc, 0, 0, 0);
        if (kb2 + 15 <= qmin) {                      // fully unmasked
#pragma unroll
          for (int r = 0; r < 4; ++r)
            accn[n] += __builtin_amdgcn_exp2f(sacc[r] - EXP_BIAS) * linv2[i][r];
        } else {                                     // diagonal block
#pragma unroll
          for (int r = 0; r < 4; ++r) {
            const int q = qmin + quad * 4 + r;
            const int key = kb2 + col;
            const float px = __builtin_amdgcn_exp2f(sacc[r] - EXP_BIAS) * linv2[i][r];
            accn[n] += (key <= q) ? px : 0.f;
          }
        }
      }
    }
#pragma unroll
    for (int n = 0; n < 4; ++n) {
      float v = accn[n];
      v += __shfl_xor(v, 16, 64);
      v += __shfl_xor(v, 32, 64);
      if (quad == 0) atomicAdd(&cs[kbase + n * 16 + col], v);
    }
  }

  __syncthreads();
  for (int j = tid; j < nk2; j += 256) atomicAdd(&ssum[j], cs[j]);
}

// ---------- top-k(128) of ssum[0..1919] -> mask (2049 floats) ----------
__global__ __launch_bounds__(1024) void topk_mask(
    const float* __restrict__ ssum, float* __restrict__ maskout) {
  __shared__ float sv[1920];
  for (int i = threadIdx.x; i < 1920; i += 1024) sv[i] = ssum[i];
  __syncthreads();
  for (int i = threadIdx.x; i < 2049; i += 1024) {
    float o;
    if (i >= 1921) o = 1.f;
    else if (i == 1920) o = 0.f;
    else {
      const float v = sv[i];
      int rank = 0;
      for (int j = 0; j < 1920; ++j) {
        const float w = sv[j];
        rank += (w > v) || (w == v && j < i);
      }
      o = (rank < 128) ? 1.f : 0.f;
    }
    maskout[i] = o;
  }
}

// ---------- launch ----------
extern "C" void kernel_launch(void* const* d_in, const int* in_sizes, int n_in,
                              void* d_out, int out_size, void* d_ws, size_t ws_size,
                              hipStream_t stream) {
  (void)in_sizes; (void)n_in; (void)out_size;
  const float* hs      = (const float*)d_in[0];   // 1x2048x4544
  const float* w_qkv   = (const float*)d_in[1];   // 4544x4672
  const float* w_dense = (const float*)d_in[2];   // 4544x4544
  float* out = (float*)d_out;                     // 2048*4544 + 2049

  char* ws = (char*)d_ws;
  constexpr size_t OFF_WT    = 0;                        // 4736x4544 bf16
  constexpr size_t OFF_HSB   = 43040768;                 // 2048x4544 bf16 (reused as merged)
  constexpr size_t OFF_FUSED = OFF_HSB + 18612224;       // 2048x4672 fp32
  constexpr size_t OFF_QR    = OFF_FUSED + 38273024;     // 2048x4544 bf16
  constexpr size_t OFF_KR    = OFF_QR + 18612224;        // 2048x64 bf16
  constexpr size_t OFF_VT    = OFF_KR + 262144;          // 64x2048 bf16
  constexpr size_t OFF_SS    = OFF_VT + 262144;          // 2048 fp32
  constexpr size_t OFF_F2    = OFF_SS + 8192;            // 2048x4672 fp32 (split-K C1)
  constexpr size_t WS_NEED   = OFF_F2 + 38273024;        // ~150.1 MiB

  ushort_t* wT     = (ushort_t*)(ws + OFF_WT);
  ushort_t* hsb    = (ushort_t*)(ws + OFF_HSB);
  float*    fused  = (float*)(ws + OFF_FUSED);
  ushort_t* qr     = (ushort_t*)(ws + OFF_QR);
  ushort_t* kr     = (ushort_t*)(ws + OFF_KR);
  ushort_t* vt     = (ushort_t*)(ws + OFF_VT);
  float*    ssum   = (float*)(ws + OFF_SS);
  float*    fused1 = (float*)(ws + OFF_F2);

  const int split = (ws_size >= WS_NEED) ? 1 : 0;        // fall back if ws too small

  f32_to_bf16_vec<<<4544, 256, 0, stream>>>(hs, hsb, 2048 * 4544 / 8);
  transpose_w_bf16<<<dim3(148, 142), 256, 0, stream>>>(w_qkv, wT, 4672, 4544);
  if (split) {
    gemm_bt_128<<<dim3(32, 37), 256, 0, stream>>>(hsb, wT, fused, fused1, 4672, 4544, 4672, 1);
    rope_split<<<2048, 256, 0, stream>>>(fused, fused1, 1, qr, kr, vt, ssum);
  } else {
    gemm_bt_128<<<dim3(16, 37), 256, 0, stream>>>(hsb, wT, fused, fused, 4672, 4544, 4672, 0);
    rope_split<<<2048, 256, 0, stream>>>(fused, fused, 0, qr, kr, vt, ssum);
  }
  transpose_w_bf16<<<dim3(144, 142), 256, 0, stream>>>(w_dense, wT, 4544, 4544);
  attn_flash<<<dim3(16, 71), 256, 0, stream>>>(qr, kr, vt, hsb, ssum);
  topk_mask<<<1, 1024, 0, stream>>>(ssum, out + (size_t)2048 * 4544);
  if (split) {
    gemm_bt_128<<<dim3(32, 36), 256, 0, stream>>>(hsb, wT, out, fused1, 4544, 4544, 4544, 1);
    add_inplace_f4<<<9088, 256, 0, stream>>>(out, fused1, 2048 * 4544 / 4);
  } else {
    gemm_bt_128<<<dim3(16, 36), 256, 0, stream>>>(hsb, wT, out, out, 4544, 4544, 4544, 0);
  }
}